// Round 1
// baseline (727.731 us; speedup 1.0000x reference)
//
#include <hip/hip_runtime.h>
#include <hip/hip_bf16.h>

#define SEQ   101
#define BATCH 16384
#define INP   9
#define HID   32
#define NOUT  3
#define NG    128      // 4*HID gate rows
#define HS    3232     // HID*SEQ

__device__ __forceinline__ float fast_sigmoid(float v) {
    return __builtin_amdgcn_rcpf(1.f + __expf(-v));
}
__device__ __forceinline__ float fast_tanh(float v) {
    return 1.f - 2.f * __builtin_amdgcn_rcpf(1.f + __expf(2.f * v));
}

// Transpose weights to k-major so per-k row-quads are contiguous (s_load_dwordx4),
// and combine the two biases.
__global__ void prep_kernel(const float* __restrict__ W_ih, const float* __restrict__ W_hh,
                            const float* __restrict__ b_ih, const float* __restrict__ b_hh,
                            float* __restrict__ WT_ih, float* __restrict__ WT_hh,
                            float* __restrict__ biasc) {
    int g = threadIdx.x;  // gate row 0..127
    if (g < NG) {
        for (int k = 0; k < HID; ++k) WT_hh[k * NG + g] = W_hh[g * HID + k];
        for (int i = 0; i < INP; ++i) WT_ih[i * NG + g] = W_ih[g * INP + i];
        biasc[g] = b_ih[g] + b_hh[g];
    }
}

// Block = 512 threads = 8 waves handling 64 batch elements.
// Wave w owns hidden outputs [4w, 4w+4) -> 16 gate rows. h exchanged via LDS,
// stored transposed h[k][b_local] so lane access is stride-1 (conflict-free).
__global__ __launch_bounds__(512) void lstm_kernel(
    const float* __restrict__ x,       // [SEQ][BATCH][INP]
    const float* __restrict__ WT_ih,   // [INP][NG]
    const float* __restrict__ WT_hh,   // [HID][NG]
    const float* __restrict__ biasc,   // [NG]
    const float* __restrict__ W_lin,   // [NOUT][HS]
    float* __restrict__ acc)           // [BATCH][NOUT] fp32 accumulators
{
    __shared__ float h_lds[HID][64];
    const int lane = threadIdx.x & 63;
    const int w    = __builtin_amdgcn_readfirstlane(threadIdx.x >> 6);  // 0..7
    const int r0   = w * 4;            // my hidden rows r0..r0+3
    const int b0   = blockIdx.x * 64;
    const int b    = b0 + lane;

    for (int i = threadIdx.x; i < HID * 64; i += 512) (&h_lds[0][0])[i] = 0.f;

    float bias[4][4];
#pragma unroll
    for (int g = 0; g < 4; ++g) {
        float4 bv = *reinterpret_cast<const float4*>(&biasc[g * HID + r0]);
        bias[g][0] = bv.x; bias[g][1] = bv.y; bias[g][2] = bv.z; bias[g][3] = bv.w;
    }
    float c[4] = {0.f, 0.f, 0.f, 0.f};
    __syncthreads();

    for (int s = 0; s < SEQ; ++s) {
        float xv[INP];
        const float* xp = x + (size_t)(s * BATCH + b) * INP;
#pragma unroll
        for (int i = 0; i < INP; ++i) xv[i] = xp[i];

        float ga[4][4];
#pragma unroll
        for (int g = 0; g < 4; ++g)
#pragma unroll
            for (int j = 0; j < 4; ++j) ga[g][j] = bias[g][j];

        // input projection (W uniform -> scalar loads; x per-lane vector)
#pragma unroll
        for (int i = 0; i < INP; ++i) {
#pragma unroll
            for (int g = 0; g < 4; ++g) {
                float4 wv = *reinterpret_cast<const float4*>(&WT_ih[i * NG + g * HID + r0]);
                ga[g][0] = fmaf(wv.x, xv[i], ga[g][0]);
                ga[g][1] = fmaf(wv.y, xv[i], ga[g][1]);
                ga[g][2] = fmaf(wv.z, xv[i], ga[g][2]);
                ga[g][3] = fmaf(wv.w, xv[i], ga[g][3]);
            }
        }
        // hidden recurrence
#pragma unroll
        for (int k = 0; k < HID; ++k) {
            float hk = h_lds[k][lane];
#pragma unroll
            for (int g = 0; g < 4; ++g) {
                float4 wv = *reinterpret_cast<const float4*>(&WT_hh[k * NG + g * HID + r0]);
                ga[g][0] = fmaf(wv.x, hk, ga[g][0]);
                ga[g][1] = fmaf(wv.y, hk, ga[g][1]);
                ga[g][2] = fmaf(wv.z, hk, ga[g][2]);
                ga[g][3] = fmaf(wv.w, hk, ga[g][3]);
            }
        }

        float hn[4];
#pragma unroll
        for (int j = 0; j < 4; ++j) {
            float ig = fast_sigmoid(ga[0][j]);
            float fg = fast_sigmoid(ga[1][j]);
            float gg = fast_tanh(ga[2][j]);
            float og = fast_sigmoid(ga[3][j]);
            float cn = fmaf(fg, c[j], ig * gg);
            c[j] = cn;
            hn[j] = og * fast_tanh(cn);
        }

        __syncthreads();   // all reads of old h complete
#pragma unroll
        for (int j = 0; j < 4; ++j) h_lds[r0 + j][lane] = hn[j];

        // Fused final linear: block blk32 = s*B+b -> row r, cols slot*32+r0..+3
        unsigned blk32 = (unsigned)(s * BATCH + b);
        unsigned r     = blk32 / 101u;
        unsigned slot  = blk32 - r * 101u;
        const float* wl = W_lin + slot * HID + r0;
        float4 w0 = *reinterpret_cast<const float4*>(wl);
        float4 w1 = *reinterpret_cast<const float4*>(wl + HS);
        float4 w2 = *reinterpret_cast<const float4*>(wl + 2 * HS);
        float p0 = w0.x * hn[0] + w0.y * hn[1] + w0.z * hn[2] + w0.w * hn[3];
        float p1 = w1.x * hn[0] + w1.y * hn[1] + w1.z * hn[2] + w1.w * hn[3];
        float p2 = w2.x * hn[0] + w2.y * hn[1] + w2.z * hn[2] + w2.w * hn[3];

        // <=2 distinct rows per wave (64 consecutive b, row len 101 blocks)
        unsigned rmin = (unsigned)(s * BATCH + b0) / 101u;
        bool low = (r == rmin);
        float a0 = low ? p0 : 0.f, a1 = low ? p1 : 0.f, a2 = low ? p2 : 0.f;
        float d0 = low ? 0.f : p0, d1 = low ? 0.f : p1, d2 = low ? 0.f : p2;
#pragma unroll
        for (int m = 1; m < 64; m <<= 1) {
            a0 += __shfl_xor(a0, m); a1 += __shfl_xor(a1, m); a2 += __shfl_xor(a2, m);
            d0 += __shfl_xor(d0, m); d1 += __shfl_xor(d1, m); d2 += __shfl_xor(d2, m);
        }
        if (lane == 0) {
            atomicAdd(&acc[rmin * 3 + 0], a0);
            atomicAdd(&acc[rmin * 3 + 1], a1);
            atomicAdd(&acc[rmin * 3 + 2], a2);
            if (rmin + 1u < BATCH) {
                atomicAdd(&acc[(rmin + 1u) * 3 + 0], d0);
                atomicAdd(&acc[(rmin + 1u) * 3 + 1], d1);
                atomicAdd(&acc[(rmin + 1u) * 3 + 2], d2);
            }
        }
        __syncthreads();   // h writes visible before next step's reads
    }
}

__global__ void finalize_kernel(const float* __restrict__ acc, const float* __restrict__ b_lin,
                                float* __restrict__ out) {
    int i = blockIdx.x * blockDim.x + threadIdx.x;
    if (i < BATCH * NOUT) {
        int r = i / 3;
        int o = i - r * 3;
        out[i] = acc[i] + b_lin[o];
    }
}

extern "C" void kernel_launch(void* const* d_in, const int* in_sizes, int n_in,
                              void* d_out, int out_size, void* d_ws, size_t ws_size,
                              hipStream_t stream) {
    const float* x     = (const float*)d_in[0];
    const float* W_ih  = (const float*)d_in[1];
    const float* W_hh  = (const float*)d_in[2];
    const float* b_ih  = (const float*)d_in[3];
    const float* b_hh  = (const float*)d_in[4];
    const float* W_lin = (const float*)d_in[5];
    const float* b_lin = (const float*)d_in[6];
    float* out = (float*)d_out;   // reference output dtype is float32

    // ws layout (fp32): acc[49152] | WT_hh[32*128] | WT_ih[9*128] | biasc[128]
    float* acc   = (float*)d_ws;
    float* WT_hh = acc + BATCH * NOUT;
    float* WT_ih = WT_hh + HID * NG;
    float* biasc = WT_ih + INP * NG;

    hipMemsetAsync(acc, 0, BATCH * NOUT * sizeof(float), stream);  // fresh accumulators every call
    hipLaunchKernelGGL(prep_kernel, dim3(1), dim3(128), 0, stream,
                       W_ih, W_hh, b_ih, b_hh, WT_ih, WT_hh, biasc);
    hipLaunchKernelGGL(lstm_kernel, dim3(BATCH / 64), dim3(512), 0, stream,
                       x, WT_ih, WT_hh, biasc, W_lin, acc);
    hipLaunchKernelGGL(finalize_kernel, dim3((BATCH * NOUT + 255) / 256), dim3(256), 0, stream,
                       acc, b_lin, out);
}

// Round 2
// 216.893 us; speedup vs baseline: 3.3552x; 3.3552x over previous
//
#include <hip/hip_runtime.h>
#include <hip/hip_bf16.h>

#define SEQ   101
#define BATCH 16384
#define INP   9
#define HID   32
#define NOUT  3
#define NG    128      // 4*HID gate rows
#define HSlin 3232     // HID*SEQ

typedef __attribute__((ext_vector_type(8))) short short8;   // 8 bf16 (4 VGPRs)
typedef __attribute__((ext_vector_type(4))) float f32x4;    // MFMA C/D

__device__ __forceinline__ float fast_sigmoid(float v) {
    return __builtin_amdgcn_rcpf(1.f + __expf(-v));
}
__device__ __forceinline__ float fast_tanh(float v) {
    return 1.f - 2.f * __builtin_amdgcn_rcpf(1.f + __expf(2.f * v));
}
__device__ __forceinline__ unsigned hi16_of(float f) {      // truncate to bf16
    return __float_as_uint(f) >> 16;
}
__device__ __forceinline__ unsigned lo16_of(float f) {      // residual as bf16
    unsigned u = __float_as_uint(f);
    float lo = f - __uint_as_float(u & 0xffff0000u);
    return __float_as_uint(lo) >> 16;
}

// Build per-lane B-fragments for mfma_f32_16x16x32_bf16.
// B-layout: lane l supplies B[k = 8*(l>>4)+j][col = l&15] of tile t (gate = 16t+col).
// xbt combined K-slot map (matches A-side builder in lstm_kernel):
//   k 0..7  : W_ih_hi[g][k]      (pairs x_hi)
//   k 8..15 : W_ih_lo[g][k-8]    (pairs x_hi)
//   k 16..23: W_ih_hi[g][k-16]   (pairs x_lo)
//   k 24    : W_ih_hi[g][8]  k25: W_ih_lo[g][8]  k26: W_ih_hi[g][8]  k27..31: 0
__global__ void prep_kernel(const float* __restrict__ W_ih, const float* __restrict__ W_hh,
                            const float* __restrict__ b_ih, const float* __restrict__ b_hh,
                            unsigned short* __restrict__ bhh_hi, unsigned short* __restrict__ bhh_lo,
                            unsigned short* __restrict__ xbt, float* __restrict__ biasc) {
    int tid = threadIdx.x;            // 0..511 : t = tid>>6, lane = tid&63
    int l = tid & 63;
    int t = tid >> 6;
    int g = 16 * t + (l & 15);
    int kb = 8 * (l >> 4);
    for (int j = 0; j < 8; ++j) {
        int k = kb + j;
        float whh = W_hh[g * HID + k];
        bhh_hi[tid * 8 + j] = (unsigned short)hi16_of(whh);
        bhh_lo[tid * 8 + j] = (unsigned short)lo16_of(whh);
        unsigned v;
        if      (k < 8)   v = hi16_of(W_ih[g * INP + k]);
        else if (k < 16)  v = lo16_of(W_ih[g * INP + (k - 8)]);
        else if (k < 24)  v = hi16_of(W_ih[g * INP + (k - 16)]);
        else if (k == 24) v = hi16_of(W_ih[g * INP + 8]);
        else if (k == 25) v = lo16_of(W_ih[g * INP + 8]);
        else if (k == 26) v = hi16_of(W_ih[g * INP + 8]);
        else              v = 0u;
        xbt[tid * 8 + j] = (unsigned short)v;
    }
    if (tid < NG) biasc[tid] = b_ih[tid] + b_hh[tid];
}

// One wave per 16 batch rows. Gates G[16][128] = [x|x|x-packed]*xB + h_hi*Whi + h_hi*Wlo + h_lo*Whi
// via 8 tiles of mfma_f32_16x16x32_bf16. h round-trips through padded LDS [16][33].
// D-layout: row = 4*(l>>4)+reg, col = l&15  (m89). A: row=l&15, k=8*(l>>4)+j. B: k=8*(l>>4)+j, col=l&15.
__global__ __launch_bounds__(64, 1) void lstm_kernel(
    const float* __restrict__ x,                 // [SEQ][BATCH][INP]
    const unsigned short* __restrict__ bhh_hi_g, // [8][64][8]
    const unsigned short* __restrict__ bhh_lo_g,
    const unsigned short* __restrict__ xbt_g,
    const float* __restrict__ biasc,             // [NG]
    const float* __restrict__ W_lin,             // [NOUT][HSlin]
    float* __restrict__ accp)                    // [BATCH][NOUT]+pad accumulators
{
    __shared__ float hsh[16 * 33];
    const int lane  = threadIdx.x;
    const int row16 = lane & 15;
    const int grp   = lane >> 4;
    const int b0    = blockIdx.x * 16;
    const int b     = b0 + row16;

    for (int i = lane; i < 16 * 33; i += 64) hsh[i] = 0.f;

    // Preload B-fragments + bias splats (live across all steps)
    short8 bhi[8], blo[8], xbv[8];
    f32x4 biasv[8];
#pragma unroll
    for (int t = 0; t < 8; ++t) {
        bhi[t] = *reinterpret_cast<const short8*>(bhh_hi_g + (t * 64 + lane) * 8);
        blo[t] = *reinterpret_cast<const short8*>(bhh_lo_g + (t * 64 + lane) * 8);
        xbv[t] = *reinterpret_cast<const short8*>(xbt_g    + (t * 64 + lane) * 8);
        float bg = biasc[16 * t + row16];
        biasv[t][0] = bg; biasv[t][1] = bg; biasv[t][2] = bg; biasv[t][3] = bg;
    }

    const float* hrd = &hsh[row16 * 33 + grp * 8];       // A-frag / W_lin read: 8 floats
    float*       hwr = &hsh[(grp * 4) * 33 + row16];     // h write: +r*33 + hf*16

    // lane-group masks for the packed-x A builder (see xbt map above)
    const bool srcx8 = (lane >= 48);
    const bool hiA   = (lane < 32) || (lane >= 48);      // j<2: groups 0,1,3 take hi
    const bool hiB   = (lane < 32);                      // j>=2: groups 0,1 take hi

    float cst[2][4] = {{0.f,0.f,0.f,0.f},{0.f,0.f,0.f,0.f}};
    float xv[9];
    {
        const float* xp = x + (size_t)b * INP;           // s = 0
#pragma unroll
        for (int i = 0; i < 9; ++i) xv[i] = xp[i];
    }

    for (int s = 0; s <= SEQ; ++s) {
        // h_{s-1}: A-source for step s AND the W_lin operand for step s-1
        float hv[8];
#pragma unroll
        for (int j = 0; j < 8; ++j) hv[j] = hrd[j];

        // Issue W_lin loads early (consumed after the MFMA/activation block)
        float4 wv0a, wv0b, wv1a, wv1b, wv2a, wv2b;
        unsigned rmin = 0; bool low = true;
        if (s > 0) {
            unsigned blk  = (unsigned)(s - 1) * BATCH + (unsigned)b;
            unsigned r    = blk / 101u;
            unsigned slot = blk - r * 101u;
            rmin = ((unsigned)(s - 1) * BATCH + (unsigned)b0) / 101u;
            low  = (r == rmin);
            const float* wl = W_lin + slot * HID + grp * 8;
            wv0a = *(const float4*)(wl);
            wv0b = *(const float4*)(wl + 4);
            wv1a = *(const float4*)(wl + HSlin);
            wv1b = *(const float4*)(wl + HSlin + 4);
            wv2a = *(const float4*)(wl + 2 * HSlin);
            wv2b = *(const float4*)(wl + 2 * HSlin + 4);
        }

        if (s < SEQ) {
            // ---- packed-x A fragment (branchless, masks precomputed) ----
            short8 xa;
            float xv8 = xv[8];
#pragma unroll
            for (int j = 0; j < 8; ++j) {
                float f = srcx8 ? xv8 : xv[j];
                unsigned u  = __float_as_uint(f);
                unsigned hi = u >> 16;
                float lof   = f - __uint_as_float(u & 0xffff0000u);
                unsigned lo = __float_as_uint(lof) >> 16;
                bool ishi   = (j < 2) ? hiA : hiB;
                unsigned sel = ishi ? hi : lo;
                if (j >= 3) sel = srcx8 ? 0u : sel;
                xa[j] = (short)sel;
            }
            // ---- prefetch next step's x (independent of recurrence) ----
            float xn[9];
            if (s < SEQ - 1) {
                const float* xpn = x + ((size_t)(s + 1) * BATCH + b) * INP;
#pragma unroll
                for (int i = 0; i < 9; ++i) xn[i] = xpn[i];
            }
            // ---- h split-bf16 A fragments ----
            short8 hahi, halo;
#pragma unroll
            for (int j = 0; j < 8; ++j) {
                unsigned u = __float_as_uint(hv[j]);
                hahi[j] = (short)(u >> 16);
                float lof = hv[j] - __uint_as_float(u & 0xffff0000u);
                halo[j] = (short)(__float_as_uint(lof) >> 16);
            }
            // ---- gates: 8 tiles x 4 MFMA ----
            f32x4 acc[8];
#pragma unroll
            for (int t = 0; t < 8; ++t) {
                acc[t] = __builtin_amdgcn_mfma_f32_16x16x32_bf16(xa,   xbv[t], biasv[t], 0, 0, 0);
                acc[t] = __builtin_amdgcn_mfma_f32_16x16x32_bf16(hahi, bhi[t], acc[t],   0, 0, 0);
                acc[t] = __builtin_amdgcn_mfma_f32_16x16x32_bf16(hahi, blo[t], acc[t],   0, 0, 0);
                acc[t] = __builtin_amdgcn_mfma_f32_16x16x32_bf16(halo, bhi[t], acc[t],   0, 0, 0);
            }
            // ---- activations + h write (lane holds hidden {row16, row16+16} x 4 rows) ----
#pragma unroll
            for (int hf = 0; hf < 2; ++hf) {
#pragma unroll
                for (int r = 0; r < 4; ++r) {
                    float iv = acc[0 + hf][r], fv = acc[2 + hf][r];
                    float gv = acc[4 + hf][r], ov = acc[6 + hf][r];
                    float ig = fast_sigmoid(iv);
                    float fg = fast_sigmoid(fv);
                    float gg = fast_tanh(gv);
                    float og = fast_sigmoid(ov);
                    float cn = fmaf(fg, cst[hf][r], ig * gg);
                    cst[hf][r] = cn;
                    hwr[r * 33 + hf * 16] = og * fast_tanh(cn);
                }
            }
            if (s < SEQ - 1) {
#pragma unroll
                for (int i = 0; i < 9; ++i) xv[i] = xn[i];
            }
        }

        // ---- fused final linear for step s-1 (<=2 output rows per wave) ----
        if (s > 0) {
            float p0 = wv0a.x*hv[0] + wv0a.y*hv[1] + wv0a.z*hv[2] + wv0a.w*hv[3]
                     + wv0b.x*hv[4] + wv0b.y*hv[5] + wv0b.z*hv[6] + wv0b.w*hv[7];
            float p1 = wv1a.x*hv[0] + wv1a.y*hv[1] + wv1a.z*hv[2] + wv1a.w*hv[3]
                     + wv1b.x*hv[4] + wv1b.y*hv[5] + wv1b.z*hv[6] + wv1b.w*hv[7];
            float p2 = wv2a.x*hv[0] + wv2a.y*hv[1] + wv2a.z*hv[2] + wv2a.w*hv[3]
                     + wv2b.x*hv[4] + wv2b.y*hv[5] + wv2b.z*hv[6] + wv2b.w*hv[7];
            float a0 = low ? p0 : 0.f, a1 = low ? p1 : 0.f, a2 = low ? p2 : 0.f;
            float d0 = low ? 0.f : p0, d1 = low ? 0.f : p1, d2 = low ? 0.f : p2;
#pragma unroll
            for (int m = 1; m < 64; m <<= 1) {
                a0 += __shfl_xor(a0, m); a1 += __shfl_xor(a1, m); a2 += __shfl_xor(a2, m);
                d0 += __shfl_xor(d0, m); d1 += __shfl_xor(d1, m); d2 += __shfl_xor(d2, m);
            }
            if (lane == 0) {
                atomicAdd(&accp[rmin * 3 + 0], a0);
                atomicAdd(&accp[rmin * 3 + 1], a1);
                atomicAdd(&accp[rmin * 3 + 2], a2);
                // rmin+1 may be 16384 only when d==0; accp has pad slots
                atomicAdd(&accp[(rmin + 1u) * 3 + 0], d0);
                atomicAdd(&accp[(rmin + 1u) * 3 + 1], d1);
                atomicAdd(&accp[(rmin + 1u) * 3 + 2], d2);
            }
        }
    }
}

__global__ void finalize_kernel(const float* __restrict__ acc, const float* __restrict__ b_lin,
                                float* __restrict__ out) {
    int i = blockIdx.x * blockDim.x + threadIdx.x;
    if (i < BATCH * NOUT) {
        int r = i / 3;
        int o = i - r * 3;
        out[i] = acc[i] + b_lin[o];
    }
}

extern "C" void kernel_launch(void* const* d_in, const int* in_sizes, int n_in,
                              void* d_out, int out_size, void* d_ws, size_t ws_size,
                              hipStream_t stream) {
    const float* x     = (const float*)d_in[0];
    const float* W_ih  = (const float*)d_in[1];
    const float* W_hh  = (const float*)d_in[2];
    const float* b_ih  = (const float*)d_in[3];
    const float* b_hh  = (const float*)d_in[4];
    const float* W_lin = (const float*)d_in[5];
    const float* b_lin = (const float*)d_in[6];
    float* out = (float*)d_out;

    // ws: acc[49160] f32 | bhh_hi[4096] u16 | bhh_lo[4096] u16 | xbt[4096] u16 | biasc[128] f32
    float* accp = (float*)d_ws;
    unsigned short* bhh_hi = (unsigned short*)(accp + 49160);
    unsigned short* bhh_lo = bhh_hi + 4096;
    unsigned short* xbt    = bhh_lo + 4096;
    float* biasc = (float*)(xbt + 4096);

    hipMemsetAsync(accp, 0, 49160 * sizeof(float), stream);
    hipLaunchKernelGGL(prep_kernel, dim3(1), dim3(512), 0, stream,
                       W_ih, W_hh, b_ih, b_hh, bhh_hi, bhh_lo, xbt, biasc);
    hipLaunchKernelGGL(lstm_kernel, dim3(BATCH / 16), dim3(64), 0, stream,
                       x, bhh_hi, bhh_lo, xbt, biasc, W_lin, accp);
    hipLaunchKernelGGL(finalize_kernel, dim3((BATCH * NOUT + 255) / 256), dim3(256), 0, stream,
                       accp, b_lin, out);
}